// Round 13
// baseline (278.970 us; speedup 1.0000x reference)
//
// GraphSAGE MI355X — R13: agg inner loop de-VALU'd (×4-padded adjacency with
// dummy zero row -> no masking; float2 packed accumulation; true deg[] array)
#include <hip/hip_runtime.h>

#define D 128
#define NBK_MAX 512
#define EPB 4096        // edges per bucket-count / binscatter block
#define BSLACK 1024     // per-bucket csr slack for ×4 padding (256 nodes × 3 + round)

typedef __attribute__((ext_vector_type(4))) float f32x4;
typedef __attribute__((ext_vector_type(8))) short bf16x8;
typedef unsigned short ushort_t;
typedef unsigned int uint_t;

__device__ inline ushort_t f2b(float f) {   // fp32 -> bf16 RNE
    uint_t u = __float_as_uint(f);
    u += 0x7FFF + ((u >> 16) & 1);
    return (ushort_t)(u >> 16);
}

// ===========================================================================
// Stage 0: per-bucket edge counts (LDS histogram; 391*391 global atomics).
// ===========================================================================
__global__ __launch_bounds__(256) void k_bucket_count(const int* __restrict__ ei,
                                                      int* __restrict__ bcnt,
                                                      int E, int nbk)
{
    __shared__ int hist[NBK_MAX];
    const int t = threadIdx.x;
    const int e0 = blockIdx.x * EPB;
    for (int i = t; i < nbk; i += 256) hist[i] = 0;
    __syncthreads();
    #pragma unroll
    for (int i = 0; i < 16; i++) {
        int e = e0 + i * 256 + t;
        if (e < E) atomicAdd(&hist[ei[E + e] >> 8], 1);
    }
    __syncthreads();
    for (int b = t; b < nbk; b += 256) {
        int c = hist[b];
        if (c) atomicAdd(&bcnt[b], c);
    }
}

// exclusive scan of nbk (<=512) bucket counts -> bbase (true bases, pristine,
// bbase[nbk]=E) and fill (mutable cursors)
__global__ __launch_bounds__(512) void k_scanb(const int* __restrict__ bcnt, int nbk,
                                               int* __restrict__ bbase,
                                               int* __restrict__ fill, int E)
{
    __shared__ int s[512];
    int t = threadIdx.x;
    int v = (t < nbk) ? bcnt[t] : 0;
    s[t] = v;
    __syncthreads();
    for (int o = 1; o < 512; o <<= 1) {
        int add = (t >= o) ? s[t - o] : 0;
        __syncthreads();
        s[t] += add;
        __syncthreads();
    }
    if (t < nbk) {
        int ex = s[t] - v;   // exclusive
        bbase[t] = ex;
        fill[t]  = ex;
    }
    if (t == 0) bbase[nbk] = E;
}

// ===========================================================================
// Stage 1: group edges by dst-bucket into eb (u32 {loc8<<24 | src24}).
// Single-block-owned lines -> no cross-XCD partial-line writebacks.
// ===========================================================================
__global__ __launch_bounds__(256) void k_binscatter(const int* __restrict__ ei,
                                                    int* __restrict__ fill,
                                                    uint_t* __restrict__ eb,
                                                    int E, int nbk)
{
    __shared__ int hist[NBK_MAX];
    __shared__ int gbase[NBK_MAX];
    const int t = threadIdx.x;
    const int e0 = blockIdx.x * EPB;

    for (int i = t; i < nbk; i += 256) hist[i] = 0;
    __syncthreads();

    int src[16], dst[16], rank[16];
    #pragma unroll
    for (int i = 0; i < 16; i++) {
        int e = e0 + i * 256 + t;
        bool ok = (e < E);
        src[i]  = ok ? ei[e] : 0;
        dst[i]  = ok ? ei[E + e] : -1;
        rank[i] = ok ? atomicAdd(&hist[dst[i] >> 8], 1) : 0;
    }
    __syncthreads();
    for (int b = t; b < nbk; b += 256) {
        int c = hist[b];
        gbase[b] = c ? atomicAdd(&fill[b], c) : 0;
    }
    __syncthreads();
    #pragma unroll
    for (int i = 0; i < 16; i++) {
        if (dst[i] >= 0) {
            int pos = gbase[dst[i] >> 8] + rank[i];
            eb[pos] = ((uint_t)(dst[i] & 255) << 24) | (uint_t)src[i];
        }
    }
}

// ===========================================================================
// Stage 2: one block per bucket. Histogram node-locs -> padded scan
// (pcnt = (cnt+3)&~3) -> row_ptr (padded starts) + deg (true counts) ->
// scatter src + fill dummy pads (zero row index) into csr_src.
// csr region for bucket b starts at bbase[b] + BSLACK*b.
// ===========================================================================
__global__ __launch_bounds__(256) void k_csr_fine(const uint_t* __restrict__ eb,
                                                  const int* __restrict__ bbase,
                                                  int* __restrict__ row_ptr,
                                                  int* __restrict__ deg,
                                                  int* __restrict__ csr_src,
                                                  int n, int dummy)
{
    __shared__ int s[256];
    __shared__ int pstart[256];
    __shared__ int hcnt[256];
    __shared__ int fl[256];
    const int b = blockIdx.x;
    const int t = threadIdx.x;
    const int base_eb  = bbase[b];
    const int cntb     = bbase[b + 1] - base_eb;
    const int base_csr = base_eb + BSLACK * b;

    hcnt[t] = 0; fl[t] = 0;
    __syncthreads();
    for (int i = t; i < cntb; i += 256)
        atomicAdd(&hcnt[eb[base_eb + i] >> 24], 1);
    __syncthreads();

    const int hc = hcnt[t];
    const int pc = (hc + 3) & ~3;
    s[t] = pc;
    __syncthreads();
    for (int o = 1; o < 256; o <<= 1) {
        int add = (t >= o) ? s[t - o] : 0;
        __syncthreads();
        s[t] += add;
        __syncthreads();
    }
    pstart[t] = s[t] - pc;   // exclusive padded start within bucket
    int node = b * 256 + t;
    if (node < n) {
        row_ptr[node] = base_csr + pstart[t];
        deg[node] = hc;
    }
    __syncthreads();

    for (int i = t; i < cntb; i += 256) {
        uint_t e = eb[base_eb + i];
        int loc = (int)(e >> 24);
        int src = (int)(e & 0x00ffffffu);
        int off = pstart[loc] + atomicAdd(&fl[loc], 1);
        csr_src[base_csr + off] = src;
    }
    // dummy pads (<=3 per node)
    for (int k = hc; k < pc; k++)
        csr_src[base_csr + pstart[t] + k] = dummy;
}

// ===========================================================================
// one-time casts: x -> bf16 (+ zero the dummy row of xb AND hb each call);
// weights -> transposed bf16 Wt[col][k]
// ===========================================================================
__global__ __launch_bounds__(256) void k_cast_x(const float* __restrict__ x,
                                                ushort_t* __restrict__ xb,
                                                ushort_t* __restrict__ hb,
                                                int total8, int dummy)
{
    int i = blockIdx.x * 256 + threadIdx.x;   // one thread = 8 elems
    if (i < total8) {
        const float4* p = (const float4*)(x + (size_t)i * 8);
        float4 a = p[0], b = p[1];
        uint4 st;
        st.x = (uint_t)f2b(a.x) | ((uint_t)f2b(a.y) << 16);
        st.y = (uint_t)f2b(a.z) | ((uint_t)f2b(a.w) << 16);
        st.z = (uint_t)f2b(b.x) | ((uint_t)f2b(b.y) << 16);
        st.w = (uint_t)f2b(b.z) | ((uint_t)f2b(b.w) << 16);
        *(uint4*)(xb + (size_t)i * 8) = st;
    } else if (i < total8 + 32) {
        int k = i - total8;                   // 0..31: 16 for xb, 16 for hb
        ushort_t* row = (k < 16 ? xb : hb);
        uint4 z = {0u, 0u, 0u, 0u};
        *(uint4*)(row + (size_t)dummy * D + (size_t)(k & 15) * 8) = z;
    }
}

__global__ __launch_bounds__(256) void k_prep_w(const float* __restrict__ W1l,
                                                const float* __restrict__ W1r,
                                                const float* __restrict__ W2l,
                                                const float* __restrict__ W2r,
                                                ushort_t* __restrict__ Wt1,
                                                ushort_t* __restrict__ Wt2)
{
    int idx = blockIdx.x * 256 + threadIdx.x;   // 128 cols * 256 k
    if (idx >= 128 * 256) return;
    int c = idx >> 8, k = idx & 255;
    float v1 = (k < D) ? W1l[(size_t)k * D + c] : W1r[(size_t)(k - D) * D + c];
    float v2 = (k < D) ? W2l[(size_t)k * D + c] : W2r[(size_t)(k - D) * D + c];
    Wt1[idx] = f2b(v1);
    Wt2[idx] = f2b(v2);
}

// ===========================================================================
// Aggregation: one wave per dst node, bf16 gather (256 B rows, 16 lanes/row,
// 4 subwarps -> 4 edges in flight). Lists are ×4-padded with a zero dummy
// row, so NO masking in the inner loop; float2 accumulation (v_pk_add_f32).
// All cross-lane ops wave-uniform.
// ===========================================================================
__global__ __launch_bounds__(256) void k_agg_csr(const ushort_t* __restrict__ featb,
                                                 const int* __restrict__ row_ptr,
                                                 const int* __restrict__ deg,
                                                 const int* __restrict__ csr_src,
                                                 ushort_t* __restrict__ meanb, int n)
{
    int gtid = blockIdx.x * 256 + threadIdx.x;
    int v    = gtid >> 6;
    if (v >= n) return;
    int lane = threadIdx.x & 63;
    int sw   = lane >> 4;
    int sl   = lane & 15;

    const int beg = row_ptr[v];
    const int dg  = deg[v];
    const int m_pad = (dg + 3) & ~3;

    const ushort_t* fb = featb + sl * 8;
    float2 acc0 = {0.f, 0.f}, acc1 = {0.f, 0.f};
    float2 acc2 = {0.f, 0.f}, acc3 = {0.f, 0.f};

    for (int base = 0; base < m_pad; base += 64) {
        int mchunk = m_pad - base; if (mchunk > 64) mchunk = 64;   // multiple of 4
        int id = csr_src[beg + base + lane];
        int steps = mchunk >> 2;
        #pragma unroll 4
        for (int t = 0; t < steps; t++) {
            int s = __shfl(id, sw + 4 * t);            // all 64 lanes active
            uint4 r = *(const uint4*)(fb + (size_t)s * D);
            acc0.x += __uint_as_float(r.x << 16);
            acc0.y += __uint_as_float(r.x & 0xffff0000u);
            acc1.x += __uint_as_float(r.y << 16);
            acc1.y += __uint_as_float(r.y & 0xffff0000u);
            acc2.x += __uint_as_float(r.z << 16);
            acc2.y += __uint_as_float(r.z & 0xffff0000u);
            acc3.x += __uint_as_float(r.w << 16);
            acc3.y += __uint_as_float(r.w & 0xffff0000u);
        }
    }

    float acc[8] = {acc0.x, acc0.y, acc1.x, acc1.y, acc2.x, acc2.y, acc3.x, acc3.y};
    #pragma unroll
    for (int q = 0; q < 8; q++) {
        acc[q] += __shfl_xor(acc[q], 16);
        acc[q] += __shfl_xor(acc[q], 32);
    }

    if (sw == 0) {
        float dinv = 1.0f / fmaxf((float)dg, 1.0f);
        uint4 st;
        st.x = (uint_t)f2b(acc[0] * dinv) | ((uint_t)f2b(acc[1] * dinv) << 16);
        st.y = (uint_t)f2b(acc[2] * dinv) | ((uint_t)f2b(acc[3] * dinv) << 16);
        st.z = (uint_t)f2b(acc[4] * dinv) | ((uint_t)f2b(acc[5] * dinv) << 16);
        st.w = (uint_t)f2b(acc[6] * dinv) | ((uint_t)f2b(acc[7] * dinv) << 16);
        *(uint4*)(meanb + (size_t)v * D + sl * 8) = st;
    }
}

// ===========================================================================
// MFMA linear: out[r] = relu?( mean[r]@Wl + b + xin[r]@Wr ), K=256, LDS-free.
// ===========================================================================
__global__ __launch_bounds__(256) void k_linear_mfma(const ushort_t* __restrict__ meanb,
                                                     const ushort_t* __restrict__ xinb,
                                                     const ushort_t* __restrict__ Wt,
                                                     const float* __restrict__ bias,
                                                     float* __restrict__ outf,
                                                     ushort_t* __restrict__ outb,
                                                     int n, int relu)
{
    const int wave  = threadIdx.x >> 6;
    const int lane  = threadIdx.x & 63;
    const int kgrp  = lane >> 4;            // 0..3
    const int rbase = blockIdx.x * 128 + wave * 32;
    const int row0  = rbase + (lane & 15);
    const int row1  = row0 + 16;

    bf16x8 a0[8], a1[8];
    {
        const ushort_t* m0 = meanb + (size_t)row0 * D + kgrp * 8;
        const ushort_t* x0 = xinb  + (size_t)row0 * D + kgrp * 8;
        const ushort_t* m1 = meanb + (size_t)row1 * D + kgrp * 8;
        const ushort_t* x1 = xinb  + (size_t)row1 * D + kgrp * 8;
        #pragma unroll
        for (int kk = 0; kk < 4; kk++) {
            a0[kk]     = *(const bf16x8*)(m0 + kk * 32);
            a0[kk + 4] = *(const bf16x8*)(x0 + kk * 32);
            a1[kk]     = *(const bf16x8*)(m1 + kk * 32);
            a1[kk + 4] = *(const bf16x8*)(x1 + kk * 32);
        }
    }

    #pragma unroll
    for (int cb = 0; cb < 8; cb++) {
        const int col = cb * 16 + (lane & 15);
        const ushort_t* wrow = Wt + (size_t)col * 256 + kgrp * 8;
        f32x4 acc0 = {0.f, 0.f, 0.f, 0.f};
        f32x4 acc1 = {0.f, 0.f, 0.f, 0.f};
        #pragma unroll
        for (int kk = 0; kk < 8; kk++) {
            bf16x8 b = *(const bf16x8*)(wrow + kk * 32);
            acc0 = __builtin_amdgcn_mfma_f32_16x16x32_bf16(a0[kk], b, acc0, 0, 0, 0);
            acc1 = __builtin_amdgcn_mfma_f32_16x16x32_bf16(a1[kk], b, acc1, 0, 0, 0);
        }
        const float bv = bias[col];
        #pragma unroll
        for (int j = 0; j < 4; j++) {
            int r0w = rbase + kgrp * 4 + j;
            if (r0w < n) {
                float v = acc0[j] + bv;
                if (relu) v = fmaxf(v, 0.f);
                if (outf) outf[(size_t)r0w * D + col] = v;
                if (outb) outb[(size_t)r0w * D + col] = f2b(v);
            }
            int r1w = r0w + 16;
            if (r1w < n) {
                float v = acc1[j] + bv;
                if (relu) v = fmaxf(v, 0.f);
                if (outf) outf[(size_t)r1w * D + col] = v;
                if (outb) outb[(size_t)r1w * D + col] = f2b(v);
            }
        }
    }
}

extern "C" void kernel_launch(void* const* d_in, const int* in_sizes, int n_in,
                              void* d_out, int out_size, void* d_ws, size_t ws_size,
                              hipStream_t stream)
{
    const float* x   = (const float*)d_in[0];
    const int*   ei  = (const int*)d_in[1];
    const float* W1l = (const float*)d_in[2];
    const float* b1  = (const float*)d_in[3];
    const float* W1r = (const float*)d_in[4];
    const float* W2l = (const float*)d_in[5];
    const float* b2  = (const float*)d_in[6];
    const float* W2r = (const float*)d_in[7];
    float* out = (float*)d_out;

    const int n = in_sizes[0] / D;   // 100000
    const int E = in_sizes[1] / 2;   // 1600000
    const int nbk = (n + 255) / 256; // 391 buckets
    const int lin_blocks = (n + 127) / 128;          // 782
    const int npad = lin_blocks * 128;               // 100096 == dummy row index

    // workspace layout (~92 MB; 102 MB proven OK in R1)
    size_t off = 0;
    auto alloc = [&](size_t bytes) { size_t o = off; off += (bytes + 511) & ~(size_t)511; return o; };
    char* ws = (char*)d_ws;
    int*      bcnt    = (int*)(ws + alloc((size_t)NBK_MAX * 4));
    int*      bbase   = (int*)(ws + alloc((size_t)(NBK_MAX + 1) * 4));
    int*      fill    = (int*)(ws + alloc((size_t)NBK_MAX * 4));
    int*      row_ptr = (int*)(ws + alloc((size_t)(n + 1) * 4));
    int*      deg     = (int*)(ws + alloc((size_t)n * 4));
    uint_t*   eb      = (uint_t*)(ws + alloc((size_t)E * 4));
    int*      csr_src = (int*)(ws + alloc(((size_t)E + (size_t)nbk * BSLACK + 64) * 4));
    ushort_t* meanb   = (ushort_t*)(ws + alloc((size_t)npad * D * 2));
    ushort_t* xb      = (ushort_t*)(ws + alloc((size_t)(npad + 1) * D * 2));
    ushort_t* hb      = (ushort_t*)(ws + alloc((size_t)(npad + 1) * D * 2));
    ushort_t* Wt1     = (ushort_t*)(ws + alloc((size_t)128 * 256 * 2));
    ushort_t* Wt2     = (ushort_t*)(ws + alloc((size_t)128 * 256 * 2));

    hipMemsetAsync(bcnt, 0, (size_t)NBK_MAX * 4, stream);

    dim3 gB((E + EPB - 1) / EPB), gN(nbk);
    // CSR build (reused by both layers)
    k_bucket_count<<<gB, 256, 0, stream>>>(ei, bcnt, E, nbk);
    k_scanb       <<<1, 512, 0, stream>>>(bcnt, nbk, bbase, fill, E);
    k_binscatter  <<<gB, 256, 0, stream>>>(ei, fill, eb, E, nbk);
    k_csr_fine    <<<gN, 256, 0, stream>>>(eb, bbase, row_ptr, deg, csr_src, n, npad);

    // one-time casts (+ zero dummy rows of xb/hb)
    const int total8 = n * D / 8;
    k_cast_x<<<dim3((total8 + 32 + 255) / 256), 256, 0, stream>>>(x, xb, hb, total8, npad);
    k_prep_w<<<dim3(128), 256, 0, stream>>>(W1l, W1r, W2l, W2r, Wt1, Wt2);

    dim3 gAgg((n + 3) / 4);
    dim3 gLin(lin_blocks);

    // layer 1 (agg gathers bf16 x; linear emits bf16 h only)
    k_agg_csr    <<<gAgg, 256, 0, stream>>>(xb, row_ptr, deg, csr_src, meanb, n);
    k_linear_mfma<<<gLin, 256, 0, stream>>>(meanb, xb, Wt1, b1, (float*)nullptr, hb, n, 1);

    // layer 2 (agg gathers bf16 h; linear writes fp32 out)
    k_agg_csr    <<<gAgg, 256, 0, stream>>>(hb, row_ptr, deg, csr_src, meanb, n);
    k_linear_mfma<<<gLin, 256, 0, stream>>>(meanb, hb, Wt2, b2, out, (ushort_t*)nullptr, n, 0);
}